// Round 1
// baseline (515.677 us; speedup 1.0000x reference)
//
#include <hip/hip_runtime.h>
#include <cmath>

// Problem constants: B=2, H=16, S=2048, D=1024, dh=64
#define SEQ 2048
#define NH  16

using bf16x8 = __attribute__((ext_vector_type(8))) short;
using f32x4  = __attribute__((ext_vector_type(4))) float;
using u16x8  = __attribute__((ext_vector_type(8))) unsigned short;
using u16x4  = __attribute__((ext_vector_type(4))) unsigned short;

#define MFMA __builtin_amdgcn_mfma_f32_16x16x32_bf16

static __device__ __forceinline__ unsigned short f2b(float f) {
  // f32 -> bf16 round-to-nearest-even (inputs are finite)
  unsigned int x = __float_as_uint(f);
  x += 0x7fffu + ((x >> 16) & 1u);
  return (unsigned short)(x >> 16);
}

static __device__ __forceinline__ u16x8 cvt8(f32x4 a, f32x4 b) {
  u16x8 o;
  o[0] = f2b(a[0]); o[1] = f2b(a[1]); o[2] = f2b(a[2]); o[3] = f2b(a[3]);
  o[4] = f2b(b[0]); o[5] = f2b(b[1]); o[6] = f2b(b[2]); o[7] = f2b(b[3]);
  return o;
}

// ---------------------------------------------------------------------------
// Kernel A: fused QKV projection.
//  q,k: C[e][s] = mfma(A=W rows(e,d-contig), B=x rows(s,d-contig))
//       -> lane holds 4 consecutive d per (s) -> packed b64 bf16 stores
//       into q_ws/k_ws laid out [bh][s][64].
//  v:   C[s][e] = mfma(A=x, B=Wv) -> lane holds 4 consecutive s per (d)
//       -> packed stores into vt_ws laid out [bh][64][S] (V transposed),
//       which is exactly what attention's PV B-fragments need.
//  q is pre-scaled by 1/sqrt(dh) * log2(e) so attention uses exp2 directly.
// ---------------------------------------------------------------------------
__global__ __launch_bounds__(256) void qkv_proj_kernel(
    const float* __restrict__ x,
    const float* __restrict__ wq, const float* __restrict__ bq,
    const float* __restrict__ wk, const float* __restrict__ bk,
    const float* __restrict__ wv, const float* __restrict__ bv,
    unsigned short* __restrict__ q_ws, unsigned short* __restrict__ k_ws,
    unsigned short* __restrict__ vt_ws) {
  const int et  = blockIdx.x;            // e-tile of 64 == head index
  const int st  = blockIdx.y;            // s-tile of 128
  const int tid = threadIdx.x;
  const int w = tid >> 6, l = tid & 63, c = l & 15, g = l >> 4;

  // 32-bf16 rows (64 B): XOR swizzle chunk^((row>>1)&3) -> 2-way (free)
  __shared__ unsigned short Xs[128 * 32];
  __shared__ unsigned short Ws[3][64 * 32];

  f32x4 qa[8], ka[8], va[2][4];
#pragma unroll
  for (int f = 0; f < 8; ++f) { qa[f] = f32x4{0.f,0.f,0.f,0.f}; ka[f] = f32x4{0.f,0.f,0.f,0.f}; }
#pragma unroll
  for (int a = 0; a < 2; ++a)
#pragma unroll
    for (int f = 0; f < 4; ++f) va[a][f] = f32x4{0.f,0.f,0.f,0.f};

  const int rx = tid >> 2;               // staging row 0..63
  const int gc = tid & 3;                // staging 8-elem chunk 0..3

  for (int kb = 0; kb < 32; ++kb) {      // K loop, BK=32
    __syncthreads();
    // stage x tile [128][32] f32 -> bf16
#pragma unroll
    for (int i = 0; i < 2; ++i) {
      int row = i * 64 + rx;
      const float* src = x + (size_t)(st * 128 + row) * 1024 + kb * 32 + gc * 8;
      f32x4 a = *(const f32x4*)src;
      f32x4 b = *(const f32x4*)(src + 4);
      int dst = row * 32 + ((gc * 8) ^ (((row >> 1) & 3) << 3));
      *(u16x8*)(&Xs[dst]) = cvt8(a, b);
    }
    // stage Wq/Wk/Wv tiles [64][32]
#pragma unroll
    for (int i = 0; i < 3; ++i) {
      const float* wsrc = (i == 0) ? wq : ((i == 1) ? wk : wv);
      const float* src = wsrc + (size_t)(et * 64 + rx) * 1024 + kb * 32 + gc * 8;
      f32x4 a = *(const f32x4*)src;
      f32x4 b = *(const f32x4*)(src + 4);
      int dst = rx * 32 + ((gc * 8) ^ (((rx >> 1) & 3) << 3));
      *(u16x8*)(&Ws[i][dst]) = cvt8(a, b);
    }
    __syncthreads();

    bf16x8 xf[8];
#pragma unroll
    for (int f = 0; f < 8; ++f) {
      int row = f * 16 + c;
      xf[f] = *(const bf16x8*)(&Xs[row * 32 + ((g * 8) ^ (((row >> 1) & 3) << 3))]);
    }
    const int rw  = w * 16 + c;
    const int sww = (g * 8) ^ (((rw >> 1) & 3) << 3);
    bf16x8 wqf = *(const bf16x8*)(&Ws[0][rw * 32 + sww]);
    bf16x8 wkf = *(const bf16x8*)(&Ws[1][rw * 32 + sww]);
    bf16x8 wvf[4];
#pragma unroll
    for (int f = 0; f < 4; ++f) {
      int row = f * 16 + c;
      wvf[f] = *(const bf16x8*)(&Ws[2][row * 32 + ((g * 8) ^ (((row >> 1) & 3) << 3))]);
    }
#pragma unroll
    for (int f = 0; f < 8; ++f) {
      qa[f] = MFMA(wqf, xf[f], qa[f], 0, 0, 0);
      ka[f] = MFMA(wkf, xf[f], ka[f], 0, 0, 0);
    }
#pragma unroll
    for (int a = 0; a < 2; ++a) {
      bf16x8 xa = xf[2 * w + a];
#pragma unroll
      for (int f = 0; f < 4; ++f) va[a][f] = MFMA(xa, wvf[f], va[a][f], 0, 0, 0);
    }
  }

  // epilogue: bias, (q) scale, bf16 pack, b64 stores
  const float QSC = 0.125f * 1.44269504088896340736f; // 1/sqrt(64) * log2(e)
  const int d0 = w * 16 + g * 4;
#pragma unroll
  for (int f = 0; f < 8; ++f) {
    int sg = st * 128 + f * 16 + c;
    int b = sg >> 11, sl = sg & 2047;
    size_t base = ((size_t)(b * NH + et) * SEQ + sl) * 64 + d0;
    u16x4 pq, pk;
#pragma unroll
    for (int r = 0; r < 4; ++r) {
      pq[r] = f2b((qa[f][r] + bq[et * 64 + d0 + r]) * QSC);
      pk[r] = f2b(ka[f][r] + bk[et * 64 + d0 + r]);
    }
    *(u16x4*)(&q_ws[base]) = pq;
    *(u16x4*)(&k_ws[base]) = pk;
  }
#pragma unroll
  for (int a = 0; a < 2; ++a) {
    int sg0 = st * 128 + w * 32 + a * 16 + g * 4;
    int b = sg0 >> 11, sl = sg0 & 2047;
#pragma unroll
    for (int f = 0; f < 4; ++f) {
      int d = f * 16 + c;
      float bias = bv[et * 64 + d];
      u16x4 pv;
#pragma unroll
      for (int r = 0; r < 4; ++r) pv[r] = f2b(va[a][f][r] + bias);
      *(u16x4*)(&vt_ws[((size_t)((b * NH + et) * 64 + d)) * SEQ + sl]) = pv;
    }
  }
}

// copy a 64-row x 128-byte bf16 tile to LDS with XOR-swizzle ((row&7)<<4 on bytes)
static __device__ __forceinline__ void stage_tile(
    unsigned short* dstLds, const unsigned short* src_base, int src_stride_u16, int tid) {
#pragma unroll
  for (int i = 0; i < 2; ++i) {
    int flat = (i * 256 + tid) * 16;
    int row  = flat >> 7;
    int colb = flat & 127;
    const unsigned short* src = src_base + (size_t)row * src_stride_u16 + (colb >> 1);
    int dst = row * 64 + ((colb ^ ((row & 7) << 4)) >> 1);
    *(u16x8*)(&dstLds[dst]) = *(const u16x8*)src;
  }
}

// ---------------------------------------------------------------------------
// Kernel B: attention per (bh, 64-q-row tile), 4 waves x 16 q-rows.
// Swapped QK^T: S'[k][q] = mfma(A=K, B=Q) -> lane c=l&15 owns q-row, holds
// k-column slices in-register -> softmax reduce = 2 shuffles, probs store =
// coalesced float4. Two passes: (1) online row max/sum, (2) recompute, write
// normalized probs, PV accumulate via LDS-transposed P and V^T tiles.
// ---------------------------------------------------------------------------
__global__ __launch_bounds__(256) void attn_kernel(
    const unsigned short* __restrict__ q_ws, const unsigned short* __restrict__ k_ws,
    const unsigned short* __restrict__ vt_ws, float* __restrict__ out) {
  const int qt  = blockIdx.x;            // q-tile of 64
  const int bh  = blockIdx.y;            // b*16 + h
  const int tid = threadIdx.x;
  const int w = tid >> 6, l = tid & 63, c = l & 15, g = l >> 4;

  __shared__ unsigned short Kl[64 * 64];
  __shared__ unsigned short Vt[64 * 64];
  __shared__ unsigned short Pl[4][16 * 64];

  const int qrow = qt * 64 + w * 16 + c;
  const unsigned short* qp = q_ws + ((size_t)bh * SEQ + qrow) * 64;
  bf16x8 qf[2];
  qf[0] = *(const bf16x8*)(qp + g * 8);
  qf[1] = *(const bf16x8*)(qp + 32 + g * 8);

  float mrun = -INFINITY, lsum = 0.f;

  // ---- pass 1: row max / denom (scores already in log2 domain, q pre-scaled)
  for (int kt = 0; kt < 32; ++kt) {
    __syncthreads();
    stage_tile(Kl, k_ws + ((size_t)bh * SEQ + kt * 64) * 64, 64, tid);
    __syncthreads();
    f32x4 sa[4];
#pragma unroll
    for (int m4 = 0; m4 < 4; ++m4) sa[m4] = f32x4{0.f,0.f,0.f,0.f};
#pragma unroll
    for (int ks = 0; ks < 2; ++ks)
#pragma unroll
      for (int m4 = 0; m4 < 4; ++m4) {
        int row = m4 * 16 + c;
        bf16x8 kf = *(const bf16x8*)(&Kl[row * 64 + ((ks * 32 + g * 8) ^ ((row & 7) << 3))]);
        sa[m4] = MFMA(kf, qf[ks], sa[m4], 0, 0, 0);
      }
    float tmax = sa[0][0];
#pragma unroll
    for (int m4 = 0; m4 < 4; ++m4)
#pragma unroll
      for (int r = 0; r < 4; ++r) tmax = fmaxf(tmax, sa[m4][r]);
    tmax = fmaxf(tmax, __shfl_xor(tmax, 16));
    tmax = fmaxf(tmax, __shfl_xor(tmax, 32));
    float mn   = fmaxf(mrun, tmax);
    float corr = exp2f(mrun - mn);
    float ts = 0.f;
#pragma unroll
    for (int m4 = 0; m4 < 4; ++m4)
#pragma unroll
      for (int r = 0; r < 4; ++r) ts += exp2f(sa[m4][r] - mn);
    ts += __shfl_xor(ts, 16);
    ts += __shfl_xor(ts, 32);
    lsum = lsum * corr + ts;
    mrun = mn;
  }
  const float invl = 1.f / lsum;

  f32x4 ctx[4];
#pragma unroll
  for (int f = 0; f < 4; ++f) ctx[f] = f32x4{0.f,0.f,0.f,0.f};

  float* probs_row = out + (size_t)2 * SEQ * 1024 + ((size_t)bh * SEQ + qrow) * SEQ;

  // ---- pass 2: recompute S, write probs, accumulate PV
  for (int kt = 0; kt < 32; ++kt) {
    __syncthreads();
    stage_tile(Kl, k_ws + ((size_t)bh * SEQ + kt * 64) * 64, 64, tid);
    stage_tile(Vt, vt_ws + (size_t)bh * 64 * SEQ + kt * 64, SEQ, tid);
    __syncthreads();
    f32x4 sa[4];
#pragma unroll
    for (int m4 = 0; m4 < 4; ++m4) sa[m4] = f32x4{0.f,0.f,0.f,0.f};
#pragma unroll
    for (int ks = 0; ks < 2; ++ks)
#pragma unroll
      for (int m4 = 0; m4 < 4; ++m4) {
        int row = m4 * 16 + c;
        bf16x8 kf = *(const bf16x8*)(&Kl[row * 64 + ((ks * 32 + g * 8) ^ ((row & 7) << 3))]);
        sa[m4] = MFMA(kf, qf[ks], sa[m4], 0, 0, 0);
      }
#pragma unroll
    for (int m4 = 0; m4 < 4; ++m4) {
      f32x4 pv;
#pragma unroll
      for (int r = 0; r < 4; ++r) pv[r] = exp2f(sa[m4][r] - mrun) * invl;
      *(f32x4*)(probs_row + kt * 64 + m4 * 16 + g * 4) = pv;   // coalesced f32x4
      u16x4 pb;
#pragma unroll
      for (int r = 0; r < 4; ++r) pb[r] = f2b(pv[r]);
      // P^T -> P redistribution via per-wave LDS, row=own q, k-chunk swizzled
      *(u16x4*)(&Pl[w][c * 64 + ((m4 * 16 + g * 4) ^ ((c & 7) << 3))]) = pb;
    }
#pragma unroll
    for (int ks = 0; ks < 2; ++ks) {
      bf16x8 pa = *(const bf16x8*)(&Pl[w][c * 64 + ((ks * 32 + g * 8) ^ ((c & 7) << 3))]);
#pragma unroll
      for (int f = 0; f < 4; ++f) {
        int row = f * 16 + c;
        bf16x8 vb = *(const bf16x8*)(&Vt[row * 64 + ((ks * 32 + g * 8) ^ ((row & 7) << 3))]);
        ctx[f] = MFMA(pa, vb, ctx[f], 0, 0, 0);
      }
    }
  }

  // ctx epilogue: C rows = q (g*4+r), cols = d (f*16+c)
  const int b = bh >> 4, h = bh & 15;
#pragma unroll
  for (int f = 0; f < 4; ++f)
#pragma unroll
    for (int r = 0; r < 4; ++r) {
      int s = qt * 64 + w * 16 + g * 4 + r;
      out[((size_t)b * SEQ + s) * 1024 + h * 64 + f * 16 + c] = ctx[f][r];
    }
}

extern "C" void kernel_launch(void* const* d_in, const int* in_sizes, int n_in,
                              void* d_out, int out_size, void* d_ws, size_t ws_size,
                              hipStream_t stream) {
  (void)in_sizes; (void)n_in; (void)out_size; (void)ws_size;
  const float* x  = (const float*)d_in[0];
  const float* wq = (const float*)d_in[1];
  const float* bq = (const float*)d_in[2];
  const float* wk = (const float*)d_in[3];
  const float* bk = (const float*)d_in[4];
  const float* wv = (const float*)d_in[5];
  const float* bv = (const float*)d_in[6];

  unsigned short* q_ws  = (unsigned short*)d_ws;        // [32][2048][64] bf16
  unsigned short* k_ws  = q_ws + (size_t)32 * SEQ * 64; // [32][2048][64] bf16
  unsigned short* vt_ws = k_ws + (size_t)32 * SEQ * 64; // [32][64][2048] bf16 (V^T)
  float* out = (float*)d_out;

  qkv_proj_kernel<<<dim3(16, 32), 256, 0, stream>>>(x, wq, bq, wk, bk, wv, bv,
                                                    q_ws, k_ws, vt_ws);
  attn_kernel<<<dim3(32, 32), 256, 0, stream>>>(q_ws, k_ws, vt_ws, out);
}

// Round 2
// 262.998 us; speedup vs baseline: 1.9608x; 1.9608x over previous
//
#include <hip/hip_runtime.h>
#include <cmath>

// Problem constants: B=2, H=16, S=2048, D=1024, dh=64
#define SEQ 2048
#define NH  16

using bf16x8 = __attribute__((ext_vector_type(8))) short;
using f32x4  = __attribute__((ext_vector_type(4))) float;
using u16x8  = __attribute__((ext_vector_type(8))) unsigned short;
using u16x4  = __attribute__((ext_vector_type(4))) unsigned short;

#define MFMA __builtin_amdgcn_mfma_f32_16x16x32_bf16

static __device__ __forceinline__ unsigned short f2b(float f) {
  // f32 -> bf16 round-to-nearest-even (inputs are finite)
  unsigned int x = __float_as_uint(f);
  x += 0x7fffu + ((x >> 16) & 1u);
  return (unsigned short)(x >> 16);
}

static __device__ __forceinline__ u16x8 cvt8(f32x4 a, f32x4 b) {
  u16x8 o;
  o[0] = f2b(a[0]); o[1] = f2b(a[1]); o[2] = f2b(a[2]); o[3] = f2b(a[3]);
  o[4] = f2b(b[0]); o[5] = f2b(b[1]); o[6] = f2b(b[2]); o[7] = f2b(b[3]);
  return o;
}

// ---------------------------------------------------------------------------
// Kernel 0: one-shot f32 -> bf16 convert of x and [Wq;Wk;Wv] into workspace.
// dst layout: [0, 4M) x_bf [4096][1024]; [4M, 7M) w_bf [3072][1024].
// Memory-bound: ~36 MB total traffic.
// ---------------------------------------------------------------------------
__global__ __launch_bounds__(256) void convert_kernel(
    const float* __restrict__ x, const float* __restrict__ wq,
    const float* __restrict__ wk, const float* __restrict__ wv,
    unsigned short* __restrict__ dst) {
  int bid = blockIdx.x;
  const float* src;
  size_t off;
  if (bid < 2048)      { src = x;  off = (size_t)bid * 2048; }
  else if (bid < 2560) { src = wq; off = (size_t)(bid - 2048) * 2048; dst += 4194304; }
  else if (bid < 3072) { src = wk; off = (size_t)(bid - 2560) * 2048; dst += 4194304 + 1048576; }
  else                 { src = wv; off = (size_t)(bid - 3072) * 2048; dst += 4194304 + 2097152; }
  size_t i = off + (size_t)threadIdx.x * 8;
  f32x4 a = *(const f32x4*)(src + i);
  f32x4 b = *(const f32x4*)(src + i + 4);
  *(u16x8*)(dst + i) = cvt8(a, b);
}

// ---------------------------------------------------------------------------
// Kernel 1: m97-structure bf16 GEMM, 128x128 tile, BK=32, 4 waves (2x2),
// global_load_lds width-16 staging, source-swizzled LDS (chunk ^= (row>>1)&3)
// to break the 8-way ds_read_b128 bank conflict down to 2-way (free).
//
// VAR=0 (q,k): C[e][s] = mfma(A=W, B=x). D-rows = e (4 consecutive per lane)
//   -> packed u16x4 stores into q_ws/k_ws [bh][s][64]. q pre-scaled by
//   1/sqrt(dh)*log2(e) so attention uses exp2.
// VAR=1 (v):   C[s][e] = mfma(A=x, B=W). D-rows = s -> packed u16x4 stores
//   into vt_ws [bh][64][SEQ] (V transposed, what attention's PV B-frag wants).
// ---------------------------------------------------------------------------
template <int VAR>
__global__ __launch_bounds__(256) void gemm_qkv(
    const unsigned short* __restrict__ x_bf,   // [4096][1024]
    const unsigned short* __restrict__ w_bf,   // [3072][1024] = [wq;wk;wv]
    const float* __restrict__ bq, const float* __restrict__ bk,
    const float* __restrict__ bv,
    unsigned short* __restrict__ q_ws, unsigned short* __restrict__ k_ws,
    unsigned short* __restrict__ vt_ws) {
  const int st  = blockIdx.x;   // s-tile (128 rows of x)
  const int et  = blockIdx.y;   // e-tile (128): VAR0 over 2048 (q,k), VAR1 over 1024 (v)
  const int tid = threadIdx.x;
  const int w = tid >> 6, l = tid & 63, c = l & 15, g = l >> 4;
  const int wr = w >> 1, wc = w & 1;

  __shared__ unsigned short Xt[128 * 32];
  __shared__ unsigned short Wt[128 * 32];

  const int wrow_base = (VAR == 0 ? et * 128 : 2048 + et * 128);

  f32x4 acc[4][4];
#pragma unroll
  for (int m = 0; m < 4; ++m)
#pragma unroll
    for (int n = 0; n < 4; ++n) acc[m][n] = f32x4{0.f, 0.f, 0.f, 0.f};

  for (int kb = 0; kb < 32; ++kb) {
    __syncthreads();
#pragma unroll
    for (int i = 0; i < 2; ++i) {
      int row   = i * 64 + w * 16 + (l >> 2);
      int chunk = (l & 3) ^ ((row >> 1) & 3);   // pre-swizzled source column
      const unsigned short* gx = x_bf + (size_t)(st * 128 + row) * 1024 + kb * 32 + chunk * 8;
      const unsigned short* gw = w_bf + (size_t)(wrow_base + row) * 1024 + kb * 32 + chunk * 8;
      __builtin_amdgcn_global_load_lds(
          (const __attribute__((address_space(1))) void*)gx,
          (__attribute__((address_space(3))) void*)&Xt[(i * 64 + w * 16) * 32], 16, 0, 0);
      __builtin_amdgcn_global_load_lds(
          (const __attribute__((address_space(1))) void*)gw,
          (__attribute__((address_space(3))) void*)&Wt[(i * 64 + w * 16) * 32], 16, 0, 0);
    }
    asm volatile("s_waitcnt vmcnt(0)" ::: "memory");
    __syncthreads();

    bf16x8 af[4], bfr[4];
#pragma unroll
    for (int m = 0; m < 4; ++m) {
      int ar = wr * 64 + m * 16 + c;
      int br = wc * 64 + m * 16 + c;
      int ach = g ^ ((ar >> 1) & 3);            // swizzled read chunk
      int bch = g ^ ((br >> 1) & 3);
      if (VAR == 0) {
        af[m]  = *(const bf16x8*)(&Wt[ar * 32 + ach * 8]);
        bfr[m] = *(const bf16x8*)(&Xt[br * 32 + bch * 8]);
      } else {
        af[m]  = *(const bf16x8*)(&Xt[ar * 32 + ach * 8]);
        bfr[m] = *(const bf16x8*)(&Wt[br * 32 + bch * 8]);
      }
    }
#pragma unroll
    for (int m = 0; m < 4; ++m)
#pragma unroll
      for (int n = 0; n < 4; ++n)
        acc[m][n] = MFMA(af[m], bfr[n], acc[m][n], 0, 0, 0);
  }

  // ---- epilogue ----
  const float QSC = 0.125f * 1.44269504088896340736f; // 1/sqrt(64) * log2(e)
  if (VAR == 0) {
    const bool isq = (et < 8);
#pragma unroll
    for (int m = 0; m < 4; ++m) {
      int e0 = et * 128 + wr * 64 + m * 16 + g * 4;  // global e' in [0,2048)
      int eh = e0 & 1023;                            // index within q or k
      int h = eh >> 6, d0 = eh & 63;
#pragma unroll
      for (int n = 0; n < 4; ++n) {
        int s = st * 128 + wc * 64 + n * 16 + c;
        int b = s >> 11, sl = s & 2047;
        u16x4 p;
        if (isq) {
#pragma unroll
          for (int r = 0; r < 4; ++r) p[r] = f2b((acc[m][n][r] + bq[eh + r]) * QSC);
          *(u16x4*)(&q_ws[((size_t)(b * NH + h) * SEQ + sl) * 64 + d0]) = p;
        } else {
#pragma unroll
          for (int r = 0; r < 4; ++r) p[r] = f2b(acc[m][n][r] + bk[eh + r]);
          *(u16x4*)(&k_ws[((size_t)(b * NH + h) * SEQ + sl) * 64 + d0]) = p;
        }
      }
    }
  } else {
#pragma unroll
    for (int m = 0; m < 4; ++m) {
      int s0 = st * 128 + wr * 64 + m * 16 + g * 4;  // 4 consecutive s
      int b = s0 >> 11, sl0 = s0 & 2047;
#pragma unroll
      for (int n = 0; n < 4; ++n) {
        int e = et * 128 + wc * 64 + n * 16 + c;
        int h = e >> 6, d = e & 63;
        float bias = bv[e];
        u16x4 p;
#pragma unroll
        for (int r = 0; r < 4; ++r) p[r] = f2b(acc[m][n][r] + bias);
        *(u16x4*)(&vt_ws[((size_t)(b * NH + h) * 64 + d) * SEQ + sl0]) = p;
      }
    }
  }
}

// copy a 64-row x 128-byte bf16 tile to LDS with XOR-swizzle ((row&7)<<4 on bytes)
static __device__ __forceinline__ void stage_tile(
    unsigned short* dstLds, const unsigned short* src_base, int src_stride_u16, int tid) {
#pragma unroll
  for (int i = 0; i < 2; ++i) {
    int flat = (i * 256 + tid) * 16;
    int row  = flat >> 7;
    int colb = flat & 127;
    const unsigned short* src = src_base + (size_t)row * src_stride_u16 + (colb >> 1);
    int dst = row * 64 + ((colb ^ ((row & 7) << 4)) >> 1);
    *(u16x8*)(&dstLds[dst]) = *(const u16x8*)src;
  }
}

// ---------------------------------------------------------------------------
// Kernel 2: attention per (bh, 64-q-row tile), 4 waves x 16 q-rows.
// Swapped QK^T: S'[k][q] = mfma(A=K, B=Q) -> lane c=l&15 owns q-row, holds
// k-column slices in-register -> softmax reduce = 2 shuffles, probs store =
// coalesced float4. Two passes: (1) online row max/sum, (2) recompute, write
// normalized probs, PV accumulate via LDS-transposed P and V^T tiles.
// ---------------------------------------------------------------------------
__global__ __launch_bounds__(256) void attn_kernel(
    const unsigned short* __restrict__ q_ws, const unsigned short* __restrict__ k_ws,
    const unsigned short* __restrict__ vt_ws, float* __restrict__ out) {
  const int qt  = blockIdx.x;            // q-tile of 64
  const int bh  = blockIdx.y;            // b*16 + h
  const int tid = threadIdx.x;
  const int w = tid >> 6, l = tid & 63, c = l & 15, g = l >> 4;

  __shared__ unsigned short Kl[64 * 64];
  __shared__ unsigned short Vt[64 * 64];
  __shared__ unsigned short Pl[4][16 * 64];

  const int qrow = qt * 64 + w * 16 + c;
  const unsigned short* qp = q_ws + ((size_t)bh * SEQ + qrow) * 64;
  bf16x8 qf[2];
  qf[0] = *(const bf16x8*)(qp + g * 8);
  qf[1] = *(const bf16x8*)(qp + 32 + g * 8);

  float mrun = -INFINITY, lsum = 0.f;

  // ---- pass 1: row max / denom (scores already in log2 domain, q pre-scaled)
  for (int kt = 0; kt < 32; ++kt) {
    __syncthreads();
    stage_tile(Kl, k_ws + ((size_t)bh * SEQ + kt * 64) * 64, 64, tid);
    __syncthreads();
    f32x4 sa[4];
#pragma unroll
    for (int m4 = 0; m4 < 4; ++m4) sa[m4] = f32x4{0.f,0.f,0.f,0.f};
#pragma unroll
    for (int ks = 0; ks < 2; ++ks)
#pragma unroll
      for (int m4 = 0; m4 < 4; ++m4) {
        int row = m4 * 16 + c;
        bf16x8 kf = *(const bf16x8*)(&Kl[row * 64 + ((ks * 32 + g * 8) ^ ((row & 7) << 3))]);
        sa[m4] = MFMA(kf, qf[ks], sa[m4], 0, 0, 0);
      }
    float tmax = sa[0][0];
#pragma unroll
    for (int m4 = 0; m4 < 4; ++m4)
#pragma unroll
      for (int r = 0; r < 4; ++r) tmax = fmaxf(tmax, sa[m4][r]);
    tmax = fmaxf(tmax, __shfl_xor(tmax, 16));
    tmax = fmaxf(tmax, __shfl_xor(tmax, 32));
    float mn   = fmaxf(mrun, tmax);
    float corr = exp2f(mrun - mn);
    float ts = 0.f;
#pragma unroll
    for (int m4 = 0; m4 < 4; ++m4)
#pragma unroll
      for (int r = 0; r < 4; ++r) ts += exp2f(sa[m4][r] - mn);
    ts += __shfl_xor(ts, 16);
    ts += __shfl_xor(ts, 32);
    lsum = lsum * corr + ts;
    mrun = mn;
  }
  const float invl = 1.f / lsum;

  f32x4 ctx[4];
#pragma unroll
  for (int f = 0; f < 4; ++f) ctx[f] = f32x4{0.f,0.f,0.f,0.f};

  float* probs_row = out + (size_t)2 * SEQ * 1024 + ((size_t)bh * SEQ + qrow) * SEQ;

  // ---- pass 2: recompute S, write probs, accumulate PV
  for (int kt = 0; kt < 32; ++kt) {
    __syncthreads();
    stage_tile(Kl, k_ws + ((size_t)bh * SEQ + kt * 64) * 64, 64, tid);
    stage_tile(Vt, vt_ws + (size_t)bh * 64 * SEQ + kt * 64, SEQ, tid);
    __syncthreads();
    f32x4 sa[4];
#pragma unroll
    for (int m4 = 0; m4 < 4; ++m4) sa[m4] = f32x4{0.f,0.f,0.f,0.f};
#pragma unroll
    for (int ks = 0; ks < 2; ++ks)
#pragma unroll
      for (int m4 = 0; m4 < 4; ++m4) {
        int row = m4 * 16 + c;
        bf16x8 kf = *(const bf16x8*)(&Kl[row * 64 + ((ks * 32 + g * 8) ^ ((row & 7) << 3))]);
        sa[m4] = MFMA(kf, qf[ks], sa[m4], 0, 0, 0);
      }
#pragma unroll
    for (int m4 = 0; m4 < 4; ++m4) {
      f32x4 pv;
#pragma unroll
      for (int r = 0; r < 4; ++r) pv[r] = exp2f(sa[m4][r] - mrun) * invl;
      *(f32x4*)(probs_row + kt * 64 + m4 * 16 + g * 4) = pv;   // coalesced f32x4
      u16x4 pb;
#pragma unroll
      for (int r = 0; r < 4; ++r) pb[r] = f2b(pv[r]);
      // P^T -> P redistribution via per-wave LDS, row=own q, k-chunk swizzled
      *(u16x4*)(&Pl[w][c * 64 + ((m4 * 16 + g * 4) ^ ((c & 7) << 3))]) = pb;
    }
#pragma unroll
    for (int ks = 0; ks < 2; ++ks) {
      bf16x8 pa = *(const bf16x8*)(&Pl[w][c * 64 + ((ks * 32 + g * 8) ^ ((c & 7) << 3))]);
#pragma unroll
      for (int f = 0; f < 4; ++f) {
        int row = f * 16 + c;
        bf16x8 vb = *(const bf16x8*)(&Vt[row * 64 + ((ks * 32 + g * 8) ^ ((row & 7) << 3))]);
        ctx[f] = MFMA(pa, vb, ctx[f], 0, 0, 0);
      }
    }
  }

  // ctx epilogue: C rows = q (g*4+r), cols = d (f*16+c)
  const int b = bh >> 4, h = bh & 15;
#pragma unroll
  for (int f = 0; f < 4; ++f)
#pragma unroll
    for (int r = 0; r < 4; ++r) {
      int s = qt * 64 + w * 16 + g * 4 + r;
      out[((size_t)b * SEQ + s) * 1024 + h * 64 + f * 16 + c] = ctx[f][r];
    }
}

extern "C" void kernel_launch(void* const* d_in, const int* in_sizes, int n_in,
                              void* d_out, int out_size, void* d_ws, size_t ws_size,
                              hipStream_t stream) {
  (void)in_sizes; (void)n_in; (void)out_size; (void)ws_size;
  const float* x  = (const float*)d_in[0];
  const float* wq = (const float*)d_in[1];
  const float* bq = (const float*)d_in[2];
  const float* wk = (const float*)d_in[3];
  const float* bk = (const float*)d_in[4];
  const float* wv = (const float*)d_in[5];
  const float* bv = (const float*)d_in[6];

  unsigned short* xw_bf = (unsigned short*)d_ws;            // x_bf [4096][1024] + w_bf [3072][1024]
  unsigned short* x_bf  = xw_bf;
  unsigned short* w_bf  = xw_bf + 4194304;
  unsigned short* q_ws  = xw_bf + 7340032;                  // [32][2048][64] bf16
  unsigned short* k_ws  = q_ws + 4194304;                   // [32][2048][64] bf16
  unsigned short* vt_ws = k_ws + 4194304;                   // [32][64][2048] bf16 (V^T)
  float* out = (float*)d_out;

  convert_kernel<<<3584, 256, 0, stream>>>(x, wq, wk, wv, xw_bf);
  gemm_qkv<0><<<dim3(32, 16), 256, 0, stream>>>(x_bf, w_bf, bq, bk, bv, q_ws, k_ws, vt_ws);
  gemm_qkv<1><<<dim3(32, 8), 256, 0, stream>>>(x_bf, w_bf, bq, bk, bv, q_ws, k_ws, vt_ws);
  attn_kernel<<<dim3(32, 32), 256, 0, stream>>>(q_ws, k_ws, vt_ws, out);
}